// Round 1
// baseline (35.734 us; speedup 1.0000x reference)
//
#include <hip/hip_runtime.h>
#include <hip/hip_bf16.h>

// Problem: x[8][4096] int32 tokens in [0, 8192).
// Output: out[b][s] = # of t <= s with x[b][t] == x[b][s], as float32.
//
// Strategy: brute-force prefix scan. One block handles 256 consecutive
// positions of one row; the full row (4096 ints, 16 KB) is staged in LDS.
// Every lane scans its own prefix with int4 LDS reads (broadcast-friendly:
// all lanes walk the same addresses in lockstep -> no bank conflicts).

constexpr int B = 8;
constexpr int S = 4096;
constexpr int BLOCK = 256;

__global__ __launch_bounds__(BLOCK) void PrefixSumCounts_kernel(
    const int* __restrict__ x, float* __restrict__ out) {
  __shared__ int seq[S];

  const int b = blockIdx.y;
  const int* row = x + b * S;

  // Cooperative staging of the whole row into LDS (coalesced int4 loads).
  for (int i = threadIdx.x; i < S / 4; i += BLOCK) {
    reinterpret_cast<int4*>(seq)[i] = reinterpret_cast<const int4*>(row)[i];
  }
  __syncthreads();

  const int s = blockIdx.x * BLOCK + threadIdx.x;
  const int tok = seq[s];

  int cnt = 0;
  const int nfull = (s + 1) >> 2;  // complete int4 groups in [0, s]
  const int4* seq4 = reinterpret_cast<const int4*>(seq);
  for (int t4 = 0; t4 < nfull; ++t4) {
    int4 v = seq4[t4];
    cnt += (v.x == tok);
    cnt += (v.y == tok);
    cnt += (v.z == tok);
    cnt += (v.w == tok);
  }
  for (int t = nfull << 2; t <= s; ++t) {
    cnt += (seq[t] == tok);
  }

  out[b * S + s] = static_cast<float>(cnt);
}

extern "C" void kernel_launch(void* const* d_in, const int* in_sizes, int n_in,
                              void* d_out, int out_size, void* d_ws, size_t ws_size,
                              hipStream_t stream) {
  const int* x = reinterpret_cast<const int*>(d_in[0]);
  float* out = reinterpret_cast<float*>(d_out);

  dim3 grid(S / BLOCK, B);  // (16, 8) = 128 blocks
  dim3 block(BLOCK);
  PrefixSumCounts_kernel<<<grid, block, 0, stream>>>(x, out);
}

// Round 2
// 29.554 us; speedup vs baseline: 1.2091x; 1.2091x over previous
//
#include <hip/hip_runtime.h>
#include <hip/hip_bf16.h>

// Problem: x[8][4096] int32 tokens in [0, 8192).
// out[b][s] = # of t <= s with x[b][t] == x[b][s], as float32.
//
// Two kernels:
//  K1 (hist): per-row token histogram -> d_ws   (8 x 8192 u32 = 256 KB)
//  K2 (scan): position s scans the SHORTER side:
//     s < 2048 : cnt = matches in [0, s]                  (prefix, inclusive)
//     s >= 2048: cnt = total[tok] - matches in (s, 4095]  (suffix)
//  Max scan length 2048 instead of 4096; total work halved (33.5M cmp).
//  512 blocks x 64 threads for the scan -> 2 blocks/CU, lengths pair up
//  around the midpoint so per-CU load is roughly uniform.

constexpr int B = 8;
constexpr int S = 4096;
constexpr int V = 8192;

__global__ __launch_bounds__(1024) void hist_kernel(
    const int* __restrict__ x, unsigned* __restrict__ hist) {
  __shared__ unsigned h[V];
  const int r = blockIdx.x;
  for (int i = threadIdx.x; i < V; i += 1024) h[i] = 0u;
  __syncthreads();
  // 1024 threads x int4 = 4096 tokens exactly.
  const int4 v = reinterpret_cast<const int4*>(x + r * S)[threadIdx.x];
  atomicAdd(&h[v.x], 1u);
  atomicAdd(&h[v.y], 1u);
  atomicAdd(&h[v.z], 1u);
  atomicAdd(&h[v.w], 1u);
  __syncthreads();
  unsigned* out = hist + r * V;
  for (int i = threadIdx.x; i < V; i += 1024) out[i] = h[i];
}

__global__ __launch_bounds__(64) void scan_kernel(
    const int* __restrict__ x, const unsigned* __restrict__ hist,
    float* __restrict__ out) {
  __shared__ int seq[S];
  const int b = blockIdx.x;  // 0..511
  const int r = b >> 6;      // row (64 position-blocks per row)
  const int j = b & 63;      // position-block within row

  const int* row = x + r * S;
  for (int i = threadIdx.x; i < S / 4; i += 64) {
    reinterpret_cast<int4*>(seq)[i] = reinterpret_cast<const int4*>(row)[i];
  }
  __syncthreads();

  const int base = j * 64;
  const int s = base + threadIdx.x;
  const int tok = seq[s];
  const int4* seq4 = reinterpret_cast<const int4*>(seq);
  int cnt = 0;

  if (base < S / 2) {
    // Prefix side: matches in [0, s] (inclusive of self).
    const int G = base >> 2;  // int4 groups fully inside [0, base)
#pragma unroll 4
    for (int g = 0; g < G; ++g) {
      int4 v = seq4[g];
      cnt += (v.x == tok) + (v.y == tok) + (v.z == tok) + (v.w == tok);
    }
    for (int t = base; t <= s; ++t) cnt += (seq[t] == tok);  // <=64 iters
    out[r * S + s] = static_cast<float>(cnt);
  } else {
    // Suffix side: cnt = matches in (s, 4095]; out = total - cnt.
    const int G0 = (base + 64) >> 2;  // groups fully after this block
#pragma unroll 4
    for (int g = G0; g < S / 4; ++g) {
      int4 v = seq4[g];
      cnt += (v.x == tok) + (v.y == tok) + (v.z == tok) + (v.w == tok);
    }
    for (int t = s + 1; t < base + 64; ++t) cnt += (seq[t] == tok);
    const unsigned total = hist[r * V + tok];
    out[r * S + s] = static_cast<float>(total - static_cast<unsigned>(cnt));
  }
}

extern "C" void kernel_launch(void* const* d_in, const int* in_sizes, int n_in,
                              void* d_out, int out_size, void* d_ws, size_t ws_size,
                              hipStream_t stream) {
  const int* x = reinterpret_cast<const int*>(d_in[0]);
  float* out = reinterpret_cast<float*>(d_out);
  unsigned* hist = reinterpret_cast<unsigned*>(d_ws);  // 8*8192*4 = 256 KB

  hist_kernel<<<dim3(B), dim3(1024), 0, stream>>>(x, hist);
  scan_kernel<<<dim3(B * (S / 64)), dim3(64), 0, stream>>>(x, hist, out);
}

// Round 3
// 14.630 us; speedup vs baseline: 2.4424x; 2.0200x over previous
//
#include <hip/hip_runtime.h>
#include <hip/hip_bf16.h>

// Problem: x[8][4096] int32 tokens in [0, 8192).
// out[b][s] = # of t <= s with x[b][t] == x[b][s], as float32.
//
// Single balanced kernel. Positions grouped into 64-wide groups; group j's
// prefix range [0, 64j) is scanned against each lane's token. Pair group j
// with group 63-j: combined prefix work 64j + 64(63-j) = 4032 = constant.
// One 512-thread block (8 waves) per pair -> 256 blocks = 1 block/CU, every
// wave scans an identical 504-element slice (8j for A + 8(63-j) for B).
// Scan elements are wave-uniform (scalar s_load path) -> 2 VALU per element
// visit (v_cmp sgpr-vs-vgpr + addc). Intra-group inclusive rank via a
// 64-iteration ballot loop on waves 0 (group A) and 1 (group B).
// Partials combined in LDS; no workspace, no atomics, no second kernel.

constexpr int B = 8;
constexpr int S = 4096;
constexpr int BLOCK = 512;  // 8 waves

__global__ __launch_bounds__(BLOCK) void count_kernel(
    const int* __restrict__ x, float* __restrict__ out) {
  __shared__ int pA[8][64];
  __shared__ int pB[8][64];
  __shared__ int iA[64];
  __shared__ int iB[64];

  const int bid = blockIdx.x;  // 0..255
  const int r = bid >> 5;      // row
  const int j = bid & 31;      // pair id: groups j and 63-j
  const int lane = threadIdx.x & 63;
  const int w = __builtin_amdgcn_readfirstlane(threadIdx.x >> 6);  // 0..7

  const int* row = x + r * S;
  const int baseA = 64 * j;
  const int baseB = 64 * (63 - j);
  const int tokA = row[baseA + lane];
  const int tokB = row[baseB + lane];

  // Per-wave equal slices of the two prefix ranges.
  const int qA = 8 * j;         // LA/8, multiple of 8
  const int qB = 8 * (63 - j);  // LB/8, multiple of 8
  int cntA = 0, cntB = 0;

  {
    const int a0 = qA * w, a1 = a0 + qA;
    for (int t = a0; t < a1; t += 8) {
      const int4 e0 = *reinterpret_cast<const int4*>(row + t);
      const int4 e1 = *reinterpret_cast<const int4*>(row + t + 4);
      cntA += (e0.x == tokA) + (e0.y == tokA) + (e0.z == tokA) + (e0.w == tokA);
      cntA += (e1.x == tokA) + (e1.y == tokA) + (e1.z == tokA) + (e1.w == tokA);
    }
  }
  {
    const int b0 = qB * w, b1 = b0 + qB;
    for (int t = b0; t < b1; t += 8) {
      const int4 e0 = *reinterpret_cast<const int4*>(row + t);
      const int4 e1 = *reinterpret_cast<const int4*>(row + t + 4);
      cntB += (e0.x == tokB) + (e0.y == tokB) + (e0.z == tokB) + (e0.w == tokB);
      cntB += (e1.x == tokB) + (e1.y == tokB) + (e1.z == tokB) + (e1.w == tokB);
    }
  }

  // Intra-group inclusive rank (count of equal tokens at positions <= own,
  // within the 64-token group). Wave 0 ranks group A, wave 1 ranks group B.
  int intra = 0;
  if (w < 2) {
    const int tk = (w == 0) ? tokA : tokB;
    const unsigned long long lemask = (~0ull) >> (63 - lane);  // bits 0..lane
#pragma unroll
    for (int q2 = 0; q2 < 64; ++q2) {
      const int sv = __shfl(tk, q2);
      const unsigned long long m = __ballot(tk == sv);
      if (lane == q2) intra = static_cast<int>(__popcll(m & lemask));
    }
  }

  pA[w][lane] = cntA;
  pB[w][lane] = cntB;
  if (w == 0) iA[lane] = intra;
  if (w == 1) iB[lane] = intra;
  __syncthreads();

  if (threadIdx.x < 128) {
    const bool isA = threadIdx.x < 64;
    int tot = isA ? iA[lane] : iB[lane];
#pragma unroll
    for (int ww = 0; ww < 8; ++ww) tot += isA ? pA[ww][lane] : pB[ww][lane];
    out[r * S + (isA ? baseA : baseB) + lane] = static_cast<float>(tot);
  }
}

extern "C" void kernel_launch(void* const* d_in, const int* in_sizes, int n_in,
                              void* d_out, int out_size, void* d_ws, size_t ws_size,
                              hipStream_t stream) {
  const int* x = reinterpret_cast<const int*>(d_in[0]);
  float* out = reinterpret_cast<float*>(d_out);
  count_kernel<<<dim3(B * 32), dim3(BLOCK), 0, stream>>>(x, out);
}

// Round 4
// 14.114 us; speedup vs baseline: 2.5318x; 1.0366x over previous
//
#include <hip/hip_runtime.h>
#include <hip/hip_bf16.h>

// Problem: x[8][4096] int32 tokens in [0, 8192).
// out[b][s] = # of t <= s with x[b][t] == x[b][s], as float32.
//
// Single balanced kernel, one block per group-pair (j, 63-j), 256 blocks =
// 1 block/CU, 8 waves. Wave w scans:
//   - slice [8j*w, 8j*(w+1)) of group A's prefix [0, 64j)
//   - slice [8(63-j)*w, ...) of group B's prefix [0, 64(63-j))
//   - 8 triangular elements of each group (t_local in [8w,8w+8), masked
//     t_local <= lane) -- this distributes the intra-group inclusive rank
//     across all 8 waves, replacing the old serial shfl/ballot loop.
// Every wave everywhere does exactly 504 + 16 = 520 element-visits; each
// visit is a wave-uniform value vs per-lane token: ~2 VALU (cmp + addc).
// Partials combined via LDS. No workspace, no atomics, single launch.

constexpr int B = 8;
constexpr int S = 4096;
constexpr int BLOCK = 512;  // 8 waves

__global__ __launch_bounds__(BLOCK) void count_kernel(
    const int* __restrict__ x, float* __restrict__ out) {
  __shared__ int pA[8][64];
  __shared__ int pB[8][64];

  const int bid = blockIdx.x;  // 0..255
  const int r = bid >> 5;      // row
  const int j = bid & 31;      // pair id: groups j and 63-j
  const int lane = threadIdx.x & 63;
  const int w = __builtin_amdgcn_readfirstlane(threadIdx.x >> 6);  // 0..7

  const int* row = x + r * S;
  const int baseA = 64 * j;
  const int baseB = 64 * (63 - j);
  const int tokA = row[baseA + lane];
  const int tokB = row[baseB + lane];

  const int qA = 8 * j;         // per-wave prefix slice for A
  const int qB = 8 * (63 - j);  // per-wave prefix slice for B
  int cntA = 0, cntB = 0;

  {
    const int a0 = qA * w, a1 = a0 + qA;
    for (int t = a0; t < a1; t += 8) {
      const int4 e0 = *reinterpret_cast<const int4*>(row + t);
      const int4 e1 = *reinterpret_cast<const int4*>(row + t + 4);
      cntA += (e0.x == tokA) + (e0.y == tokA) + (e0.z == tokA) + (e0.w == tokA);
      cntA += (e1.x == tokA) + (e1.y == tokA) + (e1.z == tokA) + (e1.w == tokA);
    }
  }
  {
    const int b0 = qB * w, b1 = b0 + qB;
    for (int t = b0; t < b1; t += 8) {
      const int4 e0 = *reinterpret_cast<const int4*>(row + t);
      const int4 e1 = *reinterpret_cast<const int4*>(row + t + 4);
      cntB += (e0.x == tokB) + (e0.y == tokB) + (e0.z == tokB) + (e0.w == tokB);
      cntB += (e1.x == tokB) + (e1.y == tokB) + (e1.z == tokB) + (e1.w == tokB);
    }
  }

  // Triangular (intra-group) part, distributed over waves: wave w covers
  // group-local positions [8w, 8w+8), contributing only to lanes >= t.
  {
    const int tb = 8 * w;
    const int4 a0 = *reinterpret_cast<const int4*>(row + baseA + tb);
    const int4 a1 = *reinterpret_cast<const int4*>(row + baseA + tb + 4);
    const int4 b0 = *reinterpret_cast<const int4*>(row + baseB + tb);
    const int4 b1 = *reinterpret_cast<const int4*>(row + baseB + tb + 4);
    const int sa[8] = {a0.x, a0.y, a0.z, a0.w, a1.x, a1.y, a1.z, a1.w};
    const int sb[8] = {b0.x, b0.y, b0.z, b0.w, b1.x, b1.y, b1.z, b1.w};
#pragma unroll
    for (int u = 0; u < 8; ++u) {
      const int t = tb + u;
      cntA += (sa[u] == tokA) & (lane >= t);
      cntB += (sb[u] == tokB) & (lane >= t);
    }
  }

  pA[w][lane] = cntA;
  pB[w][lane] = cntB;
  __syncthreads();

  if (threadIdx.x < 128) {
    const bool isA = threadIdx.x < 64;
    int tot = 0;
#pragma unroll
    for (int ww = 0; ww < 8; ++ww) tot += isA ? pA[ww][lane] : pB[ww][lane];
    out[r * S + (isA ? baseA : baseB) + lane] = static_cast<float>(tot);
  }
}

extern "C" void kernel_launch(void* const* d_in, const int* in_sizes, int n_in,
                              void* d_out, int out_size, void* d_ws, size_t ws_size,
                              hipStream_t stream) {
  const int* x = reinterpret_cast<const int*>(d_in[0]);
  float* out = reinterpret_cast<float*>(d_out);
  count_kernel<<<dim3(B * 32), dim3(BLOCK), 0, stream>>>(x, out);
}